// Round 8
// baseline (118.108 us; speedup 1.0000x reference)
//
#include <hip/hip_runtime.h>
#include <hip/hip_fp16.h>
#include <cstdint>

#define IN_F   4096
#define OUT_F  4096
#define BS     64      // sparsity block size
#define NB     64      // blocks per weight dim
#define N_TOK  8192
#define TM     256     // token tile per workgroup (4 waves x 64 rows)
#define BK     64      // K-slice = one sparsity block
#define NMT    (N_TOK / TM)   // 32 token tiles

typedef __attribute__((ext_vector_type(8))) _Float16       f16x8;
typedef __attribute__((ext_vector_type(8))) unsigned short u16x8;
typedef __attribute__((ext_vector_type(4))) float          f32x4;

// ---------------- workspace layout (bytes) ----------------
// xt: 2048 tiles (mt,kb) x 32 KB  (u16[256][64], pre-swizzled)
// wt: 4096 slots (br,si) x 8 KB   (u16[64][64],  pre-swizzled)
#define WS_XT_OFF      0ull
#define WS_XT_BYTES    (2048ull * 32768ull)            // 64 MiB
#define WS_WT_OFF      (WS_XT_OFF + WS_XT_BYTES)
#define WS_WT_BYTES    (4096ull * 8192ull)             // 32 MiB
#define WS_NEEDED      (WS_WT_OFF + WS_WT_BYTES)       // 96 MiB

// fp32x8 -> fp16x8 (RNE)
__device__ __forceinline__ u16x8 cvt_f16x8(const float* v) {
    u16x8 o;
#pragma unroll
    for (int j = 0; j < 8; ++j)
        o[j] = __half_as_ushort(__float2half_rn(v[j]));
    return o;
}

// wave-uniform ballot of the block-constant mask row `br`: bit kb set iff
// block (br,kb) is kept. Deterministic; every consumer derives the same
// slot order (ascending kb) from this.
__device__ __forceinline__ unsigned long long mask_ballot(
        const float* __restrict__ mask, int br, int lane) {
    float mv = mask[(size_t)(br * BS) * IN_F + (size_t)lane * BS];
    return __ballot(mv != 0.0f);
}

// ---------------------------------------------------------------------------
// Kernel 1 (combined convert): blocks [0,2048) -> x tiles; [2048,6144) -> w.
// x tile (mt,kb): u16[256][64] pre-swizzled, slot' = slot ^ (row & 7).
// Placed so XCD (mt>>2) converts the tiles its GEMM WGs will read (L2 affinity).
// w slot (br,si): kb = si-th set bit of the mask ballot (inline meta).
// ---------------------------------------------------------------------------
__global__ __launch_bounds__(256)
void convert_all_kernel(const float* __restrict__ x,
                        const float* __restrict__ w,
                        const float* __restrict__ mask,
                        unsigned short* __restrict__ xt,
                        unsigned short* __restrict__ wt) {
    const int b = blockIdx.x;
    if (b < 2048) {
        // ---- x tile: XCD-affine index (matches GEMM's xcd = b&7 mapping) ----
        const int xcd = b & 7;
        const int j   = b >> 3;              // 0..255
        const int mt  = xcd * 4 + (j >> 6);
        const int kb  = j & 63;
        unsigned short* tile = xt + (size_t)(mt * 64 + kb) * 16384;
#pragma unroll
        for (int l = 0; l < 8; ++l) {
            int g    = threadIdx.x + l * 256;            // 0..2047
            int row  = g >> 3, slot = g & 7;
            const float* src = x + (size_t)(mt * TM + row) * IN_F + kb * BK + slot * 8;
            float4 v0 = *(const float4*)src;
            float4 v1 = *(const float4*)(src + 4);
            float v[8] = {v0.x, v0.y, v0.z, v0.w, v1.x, v1.y, v1.z, v1.w};
            *(u16x8*)&tile[row * 64 + ((slot ^ (row & 7)) << 3)] = cvt_f16x8(v);
        }
    } else {
        // ---- w slot ----
        const int wb   = b - 2048;           // 0..4095
        const int br   = wb >> 6, si = wb & 63;
        const int lane = threadIdx.x & 63;
        unsigned long long ball = mask_ballot(mask, br, lane);
        if (si >= __popcll(ball)) return;
        // kb = si-th set bit (lane whose prefix-popcount equals si)
        bool fl = ((ball >> lane) & 1ull) &&
                  (__popcll(ball & ((1ull << lane) - 1ull)) == si);
        unsigned long long m2 = __ballot(fl);
        const int kb = __ffsll(m2) - 1;
        unsigned short* tile = wt + (size_t)(br * NB + si) * 4096;
#pragma unroll
        for (int l = 0; l < 2; ++l) {
            int g    = threadIdx.x + l * 256;            // 0..511
            int row  = g >> 3, slot = g & 7;
            const float* src = w + (size_t)(br * BS + row) * IN_F + kb * BK + slot * 8;
            float4 v0 = *(const float4*)src;
            float4 v1 = *(const float4*)(src + 4);
            float v[8] = {v0.x, v0.y, v0.z, v0.w, v1.x, v1.y, v1.z, v1.w};
            *(u16x8*)&tile[row * 64 + ((slot ^ (row & 7)) << 3)] = cvt_f16x8(v);
        }
    }
}

// async global->LDS, 16B per lane. LDS base wave-uniform; global per-lane.
__device__ __forceinline__ void gll16(const void* g, void* l) {
    __builtin_amdgcn_global_load_lds(
        (const __attribute__((address_space(1))) unsigned int*)g,
        (__attribute__((address_space(3))) unsigned int*)l, 16, 0, 0);
}

// ---------------------------------------------------------------------------
// Kernel 2: block-sparse GEMM, fp16 MFMA, TM=256, wave tile 64x64 (4x4 rep),
// 2-phase LDS double-buffer, inline ballot-meta.
// Phase-chunked XCD swizzle: per XCD, two sequential phases of 2 mts each ->
// per-phase xt working set = 2 mt x 64 kb x 32 KB = 4 MB = one XCD L2.
// ---------------------------------------------------------------------------
__global__ __launch_bounds__(256, 2)
void bsr_mfma5_kernel(const unsigned short* __restrict__ xt,
                      const unsigned short* __restrict__ wt,
                      const float* __restrict__ bias,
                      const float* __restrict__ mask,
                      float* __restrict__ out) {
    __shared__ unsigned short xs[2][TM * BK];   // 2 x 32 KB
    __shared__ unsigned short wsb[2][BS * BK];  // 2 x  8 KB

    const int b     = blockIdx.x;
    const int xcd   = b & 7;
    const int j     = b >> 3;           // 0..255
    const int phase = j >> 7;           // 0..1
    const int idx   = j & 127;          // br-fast within phase
    const int br    = idx >> 1;
    const int mt    = xcd * 4 + phase * 2 + (idx & 1);

    const int tid  = threadIdx.x;
    const int lane = tid & 63;
    const int wv   = tid >> 6;          // wave id 0..3 -> rows [wv*64, wv*64+64)
    const int fr   = lane & 15;
    const int kg   = lane >> 4;

    // ---- inline meta ----
    unsigned long long ball = mask_ballot(mask, br, lane);
    const int cnt = __popcll(ball);

    f32x4 acc[4][4];
#pragma unroll
    for (int a = 0; a < 4; ++a)
#pragma unroll
        for (int c = 0; c < 4; ++c) acc[a][c] = (f32x4)0.0f;

    const char* xbase = (const char*)xt;
    const char* wbase = (const char*)wt;

    // stage K-block kb (slot si) into buffer bb
    auto stage = [&](int kb, int si, int bb) {
        const char* xg = xbase + ((size_t)(mt * 64 + kb) << 15);   // 32 KB tiles
        const char* wg = wbase + ((size_t)(br * 64 + si) << 13);   //  8 KB tiles
        const int bx = wv * 8192;
#pragma unroll
        for (int q = 0; q < 8; ++q)
            gll16(xg + bx + q * 1024 + lane * 16, (char*)xs[bb] + bx + q * 1024);
        const int bw = wv * 2048;
#pragma unroll
        for (int q = 0; q < 2; ++q)
            gll16(wg + bw + q * 1024 + lane * 16, (char*)wsb[bb] + bw + q * 1024);
    };

    unsigned long long rem = ball;
    int cur = 0;
    if (cnt > 0) {
        int kb0 = __ffsll(rem) - 1;
        rem &= rem - 1;
        stage(kb0, 0, 0);
    }
    __syncthreads();

    for (int si = 0; si < cnt; ++si) {
        if (si + 1 < cnt) {                 // overlap next stage with compute
            int kbn = __ffsll(rem) - 1;
            rem &= rem - 1;
            stage(kbn, si + 1, cur ^ 1);
        }

#pragma unroll
        for (int ks = 0; ks < 2; ++ks) {
            f16x8 a[4], bfr[4];
#pragma unroll
            for (int mr = 0; mr < 4; ++mr) {
                int row = wv * 64 + mr * 16 + fr;
                a[mr] = *(const f16x8*)&xs[cur][row * 64 + (((ks * 4 + kg) ^ (row & 7)) << 3)];
            }
#pragma unroll
            for (int nr = 0; nr < 4; ++nr) {
                int row = nr * 16 + fr;
                bfr[nr] = *(const f16x8*)&wsb[cur][row * 64 + (((ks * 4 + kg) ^ (row & 7)) << 3)];
            }
#pragma unroll
            for (int mr = 0; mr < 4; ++mr)
#pragma unroll
                for (int nr = 0; nr < 4; ++nr)
                    acc[mr][nr] = __builtin_amdgcn_mfma_f32_16x16x32_f16(
                        a[mr], bfr[nr], acc[mr][nr], 0, 0, 0);
        }
        __syncthreads();   // all waves done reading cur; next stage drained
        cur ^= 1;
    }

    // ---- epilogue: bias + fp32 stores.  C/D: col=lane&15, row=(lane>>4)*4+r ----
    const int mbase = mt * TM;
    const int obase = br * BS;
#pragma unroll
    for (int nr = 0; nr < 4; ++nr) {
        float bv = bias[obase + nr * 16 + fr];
#pragma unroll
        for (int mr = 0; mr < 4; ++mr) {
#pragma unroll
            for (int r = 0; r < 4; ++r) {
                int m = mbase + wv * 64 + mr * 16 + kg * 4 + r;
                out[(size_t)m * OUT_F + obase + nr * 16 + fr] = acc[mr][nr][r] + bv;
            }
        }
    }
}

// ---------------------------------------------------------------------------
// Fallback (ws too small): fused in-loop fp16 conversion, single buffer,
// inline ballot-meta.
// ---------------------------------------------------------------------------
__global__ __launch_bounds__(256, 3)
void bsr_fused_kernel(const float* __restrict__ x,
                      const float* __restrict__ w,
                      const float* __restrict__ bias,
                      const float* __restrict__ mask,
                      float* __restrict__ out) {
    __shared__ unsigned short xs[128 * BK];
    __shared__ unsigned short wsb[BS * BK];

    const int mt   = blockIdx.x;
    const int br   = blockIdx.y;
    const int tid  = threadIdx.x;
    const int lane = tid & 63;
    const int wv   = tid >> 6;
    const int fr   = lane & 15;
    const int kg   = lane >> 4;

    const int mbase = mt * 128;
    const int obase = br * BS;

    unsigned long long ball = mask_ballot(mask, br, lane);
    const int cnt = __popcll(ball);
    unsigned long long rem = ball;

    f32x4 acc[2][4];
#pragma unroll
    for (int a = 0; a < 2; ++a)
#pragma unroll
        for (int c = 0; c < 4; ++c) acc[a][c] = (f32x4)0.0f;

    for (int si = 0; si < cnt; ++si) {
        const int kb = __ffsll(rem) - 1;
        rem &= rem - 1;
        const int kbase = kb * BS;
#pragma unroll
        for (int l = 0; l < 4; ++l) {
            int g = tid + l * 256;
            int row = g >> 3, slot = g & 7;
            const float* src = x + (size_t)(mbase + row) * IN_F + kbase + slot * 8;
            float4 v0 = *(const float4*)src;
            float4 v1 = *(const float4*)(src + 4);
            float v[8] = {v0.x, v0.y, v0.z, v0.w, v1.x, v1.y, v1.z, v1.w};
            *(u16x8*)&xs[row * BK + ((slot ^ (row & 7)) << 3)] = cvt_f16x8(v);
        }
#pragma unroll
        for (int l = 0; l < 2; ++l) {
            int g = tid + l * 256;
            int row = g >> 3, slot = g & 7;
            const float* src = w + (size_t)(obase + row) * IN_F + kbase + slot * 8;
            float4 v0 = *(const float4*)src;
            float4 v1 = *(const float4*)(src + 4);
            float v[8] = {v0.x, v0.y, v0.z, v0.w, v1.x, v1.y, v1.z, v1.w};
            *(u16x8*)&wsb[row * BK + ((slot ^ (row & 7)) << 3)] = cvt_f16x8(v);
        }
        __syncthreads();
#pragma unroll
        for (int ks = 0; ks < 2; ++ks) {
            f16x8 a[2], bfr[4];
#pragma unroll
            for (int mr = 0; mr < 2; ++mr) {
                int row = wv * 32 + mr * 16 + fr;
                a[mr] = *(const f16x8*)&xs[row * BK + (((ks * 4 + kg) ^ (row & 7)) << 3)];
            }
#pragma unroll
            for (int nr = 0; nr < 4; ++nr) {
                int row = nr * 16 + fr;
                bfr[nr] = *(const f16x8*)&wsb[row * BK + (((ks * 4 + kg) ^ (row & 7)) << 3)];
            }
#pragma unroll
            for (int mr = 0; mr < 2; ++mr)
#pragma unroll
                for (int nr = 0; nr < 4; ++nr)
                    acc[mr][nr] = __builtin_amdgcn_mfma_f32_16x16x32_f16(
                        a[mr], bfr[nr], acc[mr][nr], 0, 0, 0);
        }
        __syncthreads();
    }

#pragma unroll
    for (int nr = 0; nr < 4; ++nr) {
        float bv = bias[obase + nr * 16 + fr];
#pragma unroll
        for (int mr = 0; mr < 2; ++mr) {
#pragma unroll
            for (int r = 0; r < 4; ++r) {
                int m = mbase + wv * 32 + mr * 16 + kg * 4 + r;
                out[(size_t)m * OUT_F + obase + nr * 16 + fr] = acc[mr][nr][r] + bv;
            }
        }
    }
}

extern "C" void kernel_launch(void* const* d_in, const int* in_sizes, int n_in,
                              void* d_out, int out_size, void* d_ws, size_t ws_size,
                              hipStream_t stream) {
    const float* x    = (const float*)d_in[0];
    const float* w    = (const float*)d_in[1];
    const float* bias = (const float*)d_in[2];
    const float* mask = (const float*)d_in[3];
    float* out = (float*)d_out;

    if (ws_size >= WS_NEEDED) {
        unsigned short* xt = (unsigned short*)((char*)d_ws + WS_XT_OFF);
        unsigned short* wt = (unsigned short*)((char*)d_ws + WS_WT_OFF);
        convert_all_kernel<<<2048 + NB * NB, 256, 0, stream>>>(x, w, mask, xt, wt);
        bsr_mfma5_kernel<<<NMT * NB, 256, 0, stream>>>(xt, wt, bias, mask, out);
    } else {
        dim3 grid(N_TOK / 128, NB);
        bsr_fused_kernel<<<grid, 256, 0, stream>>>(x, w, bias, mask, out);
    }
}

// Round 9
// 116.372 us; speedup vs baseline: 1.0149x; 1.0149x over previous
//
#include <hip/hip_runtime.h>
#include <hip/hip_fp16.h>
#include <cstdint>

#define IN_F   4096
#define OUT_F  4096
#define BS     64      // sparsity block size
#define NB     64      // blocks per weight dim
#define N_TOK  8192
#define TM     256     // token tile per workgroup (4 waves x 64 rows)
#define BK     64      // K-slice = one sparsity block
#define NMT    (N_TOK / TM)   // 32 token tiles

typedef __attribute__((ext_vector_type(8))) _Float16       f16x8;
typedef __attribute__((ext_vector_type(8))) unsigned short u16x8;
typedef __attribute__((ext_vector_type(4))) float          f32x4;

// ---------------- workspace layout (bytes) ----------------
// xt: 2048 tiles (mt,kb) x 32 KB  (u16[256][64], pre-swizzled)
// wt: 4096 slots (br,si) x 8 KB   (u16[64][64],  pre-swizzled)
#define WS_XT_OFF      0ull
#define WS_XT_BYTES    (2048ull * 32768ull)            // 64 MiB
#define WS_WT_OFF      (WS_XT_OFF + WS_XT_BYTES)
#define WS_WT_BYTES    (4096ull * 8192ull)             // 32 MiB
#define WS_NEEDED      (WS_WT_OFF + WS_WT_BYTES)       // 96 MiB

// fp32x8 -> fp16x8 (RNE)
__device__ __forceinline__ u16x8 cvt_f16x8(const float* v) {
    u16x8 o;
#pragma unroll
    for (int j = 0; j < 8; ++j)
        o[j] = __half_as_ushort(__float2half_rn(v[j]));
    return o;
}

// wave-uniform ballot of the block-constant mask row `br`: bit kb set iff
// block (br,kb) is kept. Deterministic; every consumer derives the same
// slot order (ascending kb) from this.
__device__ __forceinline__ unsigned long long mask_ballot(
        const float* __restrict__ mask, int br, int lane) {
    float mv = mask[(size_t)(br * BS) * IN_F + (size_t)lane * BS];
    return __ballot(mv != 0.0f);
}

// ---------------------------------------------------------------------------
// Kernel 1a: x -> tile-ready pre-swizzled fp16, MLP-structured.
// All 16 float4 loads are issued before any convert/store so the memory
// pipe holds 16 outstanding loads per thread (launch_bounds(256,1) frees
// the register allocator to keep them live; r8's VGPR=32 serialized this).
// Tile (mt,kb): u16[256][64]; (row, slot8) at slot' = slot ^ (row & 7).
// ---------------------------------------------------------------------------
__global__ __launch_bounds__(256, 1)
void convert_x_kernel(const float* __restrict__ x, unsigned short* __restrict__ xt) {
    const int t  = blockIdx.x;          // 0..2047 (plain mapping, r6-proven)
    const int mt = t >> 6, kb = t & 63;
    unsigned short* tile = xt + (size_t)t * 16384;   // == (mt*64+kb)*16384

    float4 va[8], vb[8];
#pragma unroll
    for (int l = 0; l < 8; ++l) {
        int g   = threadIdx.x + l * 256;             // 0..2047
        int row = g >> 3, slot = g & 7;
        const float* src = x + (size_t)(mt * TM + row) * IN_F + kb * BK + slot * 8;
        va[l] = *(const float4*)src;
        vb[l] = *(const float4*)(src + 4);
    }
#pragma unroll
    for (int l = 0; l < 8; ++l) {
        int g   = threadIdx.x + l * 256;
        int row = g >> 3, slot = g & 7;
        float v[8] = {va[l].x, va[l].y, va[l].z, va[l].w,
                      vb[l].x, vb[l].y, vb[l].z, vb[l].w};
        *(u16x8*)&tile[row * 64 + ((slot ^ (row & 7)) << 3)] = cvt_f16x8(v);
    }
}

// ---------------------------------------------------------------------------
// Kernel 1b: kept W blocks -> packed [br][si] fp16 tiles, inline ballot-meta.
// Only ~410 of 4096 blocks do work (~7 MB total r/w).
// ---------------------------------------------------------------------------
__global__ __launch_bounds__(256)
void convert_w_kernel(const float* __restrict__ w,
                      const float* __restrict__ mask,
                      unsigned short* __restrict__ wt) {
    const int br   = blockIdx.y, si = blockIdx.x;
    const int lane = threadIdx.x & 63;
    unsigned long long ball = mask_ballot(mask, br, lane);
    if (si >= __popcll(ball)) return;
    // kb = si-th set bit of ball (prefix-popcount match, wave-uniform result)
    bool fl = ((ball >> lane) & 1ull) &&
              (__popcll(ball & ((1ull << lane) - 1ull)) == si);
    unsigned long long m2 = __ballot(fl);
    const int kb = __ffsll(m2) - 1;
    unsigned short* tile = wt + (size_t)(br * NB + si) * 4096;

    float4 va[2], vb[2];
#pragma unroll
    for (int l = 0; l < 2; ++l) {
        int g   = threadIdx.x + l * 256;             // 0..511
        int row = g >> 3, slot = g & 7;
        const float* src = w + (size_t)(br * BS + row) * IN_F + kb * BK + slot * 8;
        va[l] = *(const float4*)src;
        vb[l] = *(const float4*)(src + 4);
    }
#pragma unroll
    for (int l = 0; l < 2; ++l) {
        int g   = threadIdx.x + l * 256;
        int row = g >> 3, slot = g & 7;
        float v[8] = {va[l].x, va[l].y, va[l].z, va[l].w,
                      vb[l].x, vb[l].y, vb[l].z, vb[l].w};
        *(u16x8*)&tile[row * 64 + ((slot ^ (row & 7)) << 3)] = cvt_f16x8(v);
    }
}

// async global->LDS, 16B per lane. LDS base wave-uniform; global per-lane.
__device__ __forceinline__ void gll16(const void* g, void* l) {
    __builtin_amdgcn_global_load_lds(
        (const __attribute__((address_space(1))) unsigned int*)g,
        (__attribute__((address_space(3))) unsigned int*)l, 16, 0, 0);
}

// ---------------------------------------------------------------------------
// Kernel 2: block-sparse GEMM, fp16 MFMA, TM=256, wave tile 64x64 (4x4 rep),
// 2-phase LDS double-buffer, inline ballot-meta.  (byte-identical to r8)
// Phase-chunked XCD swizzle: per XCD, two sequential phases of 2 mts each ->
// per-phase xt working set = 2 mt x 64 kb x 32 KB = 4 MB = one XCD L2.
// ---------------------------------------------------------------------------
__global__ __launch_bounds__(256, 2)
void bsr_mfma5_kernel(const unsigned short* __restrict__ xt,
                      const unsigned short* __restrict__ wt,
                      const float* __restrict__ bias,
                      const float* __restrict__ mask,
                      float* __restrict__ out) {
    __shared__ unsigned short xs[2][TM * BK];   // 2 x 32 KB
    __shared__ unsigned short wsb[2][BS * BK];  // 2 x  8 KB

    const int b     = blockIdx.x;
    const int xcd   = b & 7;
    const int j     = b >> 3;           // 0..255
    const int phase = j >> 7;           // 0..1
    const int idx   = j & 127;          // br-fast within phase
    const int br    = idx >> 1;
    const int mt    = xcd * 4 + phase * 2 + (idx & 1);

    const int tid  = threadIdx.x;
    const int lane = tid & 63;
    const int wv   = tid >> 6;          // wave id 0..3 -> rows [wv*64, wv*64+64)
    const int fr   = lane & 15;
    const int kg   = lane >> 4;

    // ---- inline meta ----
    unsigned long long ball = mask_ballot(mask, br, lane);
    const int cnt = __popcll(ball);

    f32x4 acc[4][4];
#pragma unroll
    for (int a = 0; a < 4; ++a)
#pragma unroll
        for (int c = 0; c < 4; ++c) acc[a][c] = (f32x4)0.0f;

    const char* xbase = (const char*)xt;
    const char* wbase = (const char*)wt;

    // stage K-block kb (slot si) into buffer bb
    auto stage = [&](int kb, int si, int bb) {
        const char* xg = xbase + ((size_t)(mt * 64 + kb) << 15);   // 32 KB tiles
        const char* wg = wbase + ((size_t)(br * 64 + si) << 13);   //  8 KB tiles
        const int bx = wv * 8192;
#pragma unroll
        for (int q = 0; q < 8; ++q)
            gll16(xg + bx + q * 1024 + lane * 16, (char*)xs[bb] + bx + q * 1024);
        const int bw = wv * 2048;
#pragma unroll
        for (int q = 0; q < 2; ++q)
            gll16(wg + bw + q * 1024 + lane * 16, (char*)wsb[bb] + bw + q * 1024);
    };

    unsigned long long rem = ball;
    int cur = 0;
    if (cnt > 0) {
        int kb0 = __ffsll(rem) - 1;
        rem &= rem - 1;
        stage(kb0, 0, 0);
    }
    __syncthreads();

    for (int si = 0; si < cnt; ++si) {
        if (si + 1 < cnt) {                 // overlap next stage with compute
            int kbn = __ffsll(rem) - 1;
            rem &= rem - 1;
            stage(kbn, si + 1, cur ^ 1);
        }

#pragma unroll
        for (int ks = 0; ks < 2; ++ks) {
            f16x8 a[4], bfr[4];
#pragma unroll
            for (int mr = 0; mr < 4; ++mr) {
                int row = wv * 64 + mr * 16 + fr;
                a[mr] = *(const f16x8*)&xs[cur][row * 64 + (((ks * 4 + kg) ^ (row & 7)) << 3)];
            }
#pragma unroll
            for (int nr = 0; nr < 4; ++nr) {
                int row = nr * 16 + fr;
                bfr[nr] = *(const f16x8*)&wsb[cur][row * 64 + (((ks * 4 + kg) ^ (row & 7)) << 3)];
            }
#pragma unroll
            for (int mr = 0; mr < 4; ++mr)
#pragma unroll
                for (int nr = 0; nr < 4; ++nr)
                    acc[mr][nr] = __builtin_amdgcn_mfma_f32_16x16x32_f16(
                        a[mr], bfr[nr], acc[mr][nr], 0, 0, 0);
        }
        __syncthreads();   // all waves done reading cur; next stage drained
        cur ^= 1;
    }

    // ---- epilogue: bias + fp32 stores.  C/D: col=lane&15, row=(lane>>4)*4+r ----
    const int mbase = mt * TM;
    const int obase = br * BS;
#pragma unroll
    for (int nr = 0; nr < 4; ++nr) {
        float bv = bias[obase + nr * 16 + fr];
#pragma unroll
        for (int mr = 0; mr < 4; ++mr) {
#pragma unroll
            for (int r = 0; r < 4; ++r) {
                int m = mbase + wv * 64 + mr * 16 + kg * 4 + r;
                out[(size_t)m * OUT_F + obase + nr * 16 + fr] = acc[mr][nr][r] + bv;
            }
        }
    }
}

// ---------------------------------------------------------------------------
// Fallback (ws too small): fused in-loop fp16 conversion, single buffer,
// inline ballot-meta.
// ---------------------------------------------------------------------------
__global__ __launch_bounds__(256, 3)
void bsr_fused_kernel(const float* __restrict__ x,
                      const float* __restrict__ w,
                      const float* __restrict__ bias,
                      const float* __restrict__ mask,
                      float* __restrict__ out) {
    __shared__ unsigned short xs[128 * BK];
    __shared__ unsigned short wsb[BS * BK];

    const int mt   = blockIdx.x;
    const int br   = blockIdx.y;
    const int tid  = threadIdx.x;
    const int lane = tid & 63;
    const int wv   = tid >> 6;
    const int fr   = lane & 15;
    const int kg   = lane >> 4;

    const int mbase = mt * 128;
    const int obase = br * BS;

    unsigned long long ball = mask_ballot(mask, br, lane);
    const int cnt = __popcll(ball);
    unsigned long long rem = ball;

    f32x4 acc[2][4];
#pragma unroll
    for (int a = 0; a < 2; ++a)
#pragma unroll
        for (int c = 0; c < 4; ++c) acc[a][c] = (f32x4)0.0f;

    for (int si = 0; si < cnt; ++si) {
        const int kb = __ffsll(rem) - 1;
        rem &= rem - 1;
        const int kbase = kb * BS;
#pragma unroll
        for (int l = 0; l < 4; ++l) {
            int g = tid + l * 256;
            int row = g >> 3, slot = g & 7;
            const float* src = x + (size_t)(mbase + row) * IN_F + kbase + slot * 8;
            float4 v0 = *(const float4*)src;
            float4 v1 = *(const float4*)(src + 4);
            float v[8] = {v0.x, v0.y, v0.z, v0.w, v1.x, v1.y, v1.z, v1.w};
            *(u16x8*)&xs[row * BK + ((slot ^ (row & 7)) << 3)] = cvt_f16x8(v);
        }
#pragma unroll
        for (int l = 0; l < 2; ++l) {
            int g = tid + l * 256;
            int row = g >> 3, slot = g & 7;
            const float* src = w + (size_t)(obase + row) * IN_F + kbase + slot * 8;
            float4 v0 = *(const float4*)src;
            float4 v1 = *(const float4*)(src + 4);
            float v[8] = {v0.x, v0.y, v0.z, v0.w, v1.x, v1.y, v1.z, v1.w};
            *(u16x8*)&wsb[row * BK + ((slot ^ (row & 7)) << 3)] = cvt_f16x8(v);
        }
        __syncthreads();
#pragma unroll
        for (int ks = 0; ks < 2; ++ks) {
            f16x8 a[2], bfr[4];
#pragma unroll
            for (int mr = 0; mr < 2; ++mr) {
                int row = wv * 32 + mr * 16 + fr;
                a[mr] = *(const f16x8*)&xs[row * BK + (((ks * 4 + kg) ^ (row & 7)) << 3)];
            }
#pragma unroll
            for (int nr = 0; nr < 4; ++nr) {
                int row = nr * 16 + fr;
                bfr[nr] = *(const f16x8*)&wsb[row * BK + (((ks * 4 + kg) ^ (row & 7)) << 3)];
            }
#pragma unroll
            for (int mr = 0; mr < 2; ++mr)
#pragma unroll
                for (int nr = 0; nr < 4; ++nr)
                    acc[mr][nr] = __builtin_amdgcn_mfma_f32_16x16x32_f16(
                        a[mr], bfr[nr], acc[mr][nr], 0, 0, 0);
        }
        __syncthreads();
    }

#pragma unroll
    for (int nr = 0; nr < 4; ++nr) {
        float bv = bias[obase + nr * 16 + fr];
#pragma unroll
        for (int mr = 0; mr < 2; ++mr) {
#pragma unroll
            for (int r = 0; r < 4; ++r) {
                int m = mbase + wv * 32 + mr * 16 + kg * 4 + r;
                out[(size_t)m * OUT_F + obase + nr * 16 + fr] = acc[mr][nr][r] + bv;
            }
        }
    }
}

extern "C" void kernel_launch(void* const* d_in, const int* in_sizes, int n_in,
                              void* d_out, int out_size, void* d_ws, size_t ws_size,
                              hipStream_t stream) {
    const float* x    = (const float*)d_in[0];
    const float* w    = (const float*)d_in[1];
    const float* bias = (const float*)d_in[2];
    const float* mask = (const float*)d_in[3];
    float* out = (float*)d_out;

    if (ws_size >= WS_NEEDED) {
        unsigned short* xt = (unsigned short*)((char*)d_ws + WS_XT_OFF);
        unsigned short* wt = (unsigned short*)((char*)d_ws + WS_WT_OFF);
        convert_x_kernel<<<2048, 256, 0, stream>>>(x, xt);
        convert_w_kernel<<<dim3(NB, NB), 256, 0, stream>>>(w, mask, wt);
        bsr_mfma5_kernel<<<NMT * NB, 256, 0, stream>>>(xt, wt, bias, mask, out);
    } else {
        dim3 grid(N_TOK / 128, NB);
        bsr_fused_kernel<<<grid, 256, 0, stream>>>(x, w, bias, mask, out);
    }
}